// Round 9
// baseline (492.195 us; speedup 1.0000x reference)
//
#include <hip/hip_runtime.h>
#include <hip/hip_bf16.h>

#define TOKENS 16384
#define DMODEL 4096
#define NCH 8
#define CH 512
#define BM 64

typedef short s16x8 __attribute__((ext_vector_type(8)));
typedef float f32x4 __attribute__((ext_vector_type(4)));

__device__ __forceinline__ unsigned short f2bf(float f) {
    unsigned u = __float_as_uint(f);
    u += 0x7fffu + ((u >> 16) & 1u);
    return (unsigned short)(u >> 16);
}

// tanh-form GELU via single v_exp: gelu(x) = x - x/(e+1), e = exp(1.5957691*(x+0.044715x^3))
__device__ __forceinline__ float gelu_fast(float x) {
    float u = 1.5957691216057308f * x * (1.0f + 0.044715f * x * x);
    float e = __expf(u);
    return x - x * __builtin_amdgcn_rcpf(e + 1.0f);
}

// ---------------------------------------------------------------------------
// K0: weight prep into MFMA-fragment-packed layout.
// w[n][c][d] fp32 -> P[n][kt*32+nb][lane][8] bf16; the 16B at (kt,nb,lane)
// holds W[kt*32+kg*8+j][nb*16+l15], j=0..7 (kg=lane>>4, l15=lane&15).
// One (kt,nb) line = 64 lanes x 16B = 1KB contiguous -> global_load_lds ready.
// ---------------------------------------------------------------------------
__global__ __launch_bounds__(256)
void wprep_kernel(const float* __restrict__ w1, const float* __restrict__ w2,
                  unsigned short* __restrict__ p1, unsigned short* __restrict__ p2)
{
    const int lane = threadIdx.x;          // 0..63
    const int sub  = threadIdx.y;          // 0..3
    const int kt   = blockIdx.x;           // 0..15
    const int nb   = blockIdx.y * 4 + sub; // 0..31
    const int which = blockIdx.z >> 3;
    const int n     = blockIdx.z & 7;

    const int kg  = lane >> 4;
    const int l15 = lane & 15;

    const float* src = (which ? w2 : w1) + (size_t)n * CH * CH;
    unsigned short* dst = (which ? p2 : p1) + (size_t)n * CH * CH
                        + ((size_t)(kt * 32 + nb) * 64 + lane) * 8;

    unsigned short v[8];
#pragma unroll
    for (int j = 0; j < 8; ++j)
        v[j] = f2bf(src[(size_t)(kt * 32 + kg * 8 + j) * CH + nb * 16 + l15]);

    uint4 q;
    q.x = (unsigned)v[0] | ((unsigned)v[1] << 16);
    q.y = (unsigned)v[2] | ((unsigned)v[3] << 16);
    q.z = (unsigned)v[4] | ((unsigned)v[5] << 16);
    q.w = (unsigned)v[6] | ((unsigned)v[7] << 16);
    *(uint4*)dst = q;
}

// ---------------------------------------------------------------------------
// K1: fused chunk MLP, 2-phase LDS-staged-B schedule.
// grid = (TOKENS/BM, NCH) tile-fastest; block = 512 (8 waves).
// Wave owns all 64 M rows x a 64-wide N slice (acc 4x4).
// LDS: [0,64K) Xc bf16 (XOR-swizzled; aliased to H1 after GEMM1)
//      [64K,96K) B buf0   [96K,128K) B buf1   (linear packed-frag layout)
// Per kt: STAGE(next B via global_load_lds, no VGPR cost) -> ds_read A,B ->
// 16 MFMA -> __syncthreads() (vmcnt(0)+lgkmcnt(0) drain = 2-phase contract).
// ---------------------------------------------------------------------------
#define XC_BYTES (BM * CH * 2)        // 65536
#define BBUF0    XC_BYTES
#define BBUF1    (XC_BYTES + 32768)

__global__ __launch_bounds__(512, 1)
void mlp_kernel(const float* __restrict__ x,
                const unsigned short* __restrict__ p1,
                const unsigned short* __restrict__ p2,
                const float* __restrict__ b1,
                const float* __restrict__ b2,
                float* __restrict__ mid)
{
    __shared__ unsigned char lds[XC_BYTES + 2 * 32768];   // 128 KB
    const int tile = blockIdx.x;
    const int n    = blockIdx.y;
    const int tid  = threadIdx.x;
    const int wid  = tid >> 6;          // 0..7
    const int lane = tid & 63;
    const int row0 = tile * BM;

    const unsigned short* p1n = p1 + (size_t)n * CH * CH;
    const unsigned short* p2n = p2 + (size_t)n * CH * CH;

    // stage one 32KB B k-tile (kt) into LDS buffer at byte base `bufb`.
    // wave wid stages its own nb range [wid*4, wid*4+4): 4 x 1KB lines.
    auto stageB = [&](const unsigned short* pk, int kt, int bufb) {
#pragma unroll
        for (int i = 0; i < 4; ++i) {
            const unsigned short* src = pk + ((size_t)(kt * 32 + wid * 4 + i) * 64 + lane) * 8;
            unsigned char* dstp = lds + bufb + (wid * 4 + i) * 1024;  // wave-uniform
            __builtin_amdgcn_global_load_lds(
                (const __attribute__((address_space(1))) void*)src,
                (__attribute__((address_space(3))) void*)dstp,
                16, 0, 0);
        }
    };

    // ---- prologue: issue B1[kt=0] -> buf0, then stage Xc (fp32->bf16, swizzled)
    stageB(p1n, 0, BBUF0);
    {
        const float* xc = x + (size_t)row0 * DMODEL + n * CH;
#pragma unroll
        for (int it = 0; it < 16; ++it) {
            int f = it * 512 + tid;          // float4 index, 128 per row, 64 rows
            int r = f >> 7;
            int c = (f & 127) << 2;
            const float4 v = *(const float4*)(xc + (size_t)r * DMODEL + c);
            unsigned lo = (unsigned)f2bf(v.x) | ((unsigned)f2bf(v.y) << 16);
            unsigned hi = (unsigned)f2bf(v.z) | ((unsigned)f2bf(v.w) << 16);
            int byte = ((r * CH + c) * 2) ^ ((r & 7) << 4);
            *(uint2*)(lds + byte) = make_uint2(lo, hi);
        }
    }
    __syncthreads();   // drains vm (B1[0]) and lgkm (Xc writes)

    const int nwoff = wid * 64;         // wave's N offset within the chunk
    const int l15   = lane & 15;
    const int kg    = lane >> 4;

    float b1v[4], b2v[4];
#pragma unroll
    for (int ni = 0; ni < 4; ++ni) {
        int col = n * CH + nwoff + ni * 16 + l15;
        b1v[ni] = b1[col];
        b2v[ni] = b2[col];
    }

    f32x4 acc[4][4];
    auto zacc = [&]() {
#pragma unroll
        for (int mi = 0; mi < 4; ++mi)
#pragma unroll
            for (int ni = 0; ni < 4; ++ni)
                acc[mi][ni] = (f32x4){0.f, 0.f, 0.f, 0.f};
    };

    // one kt compute step: ds_read A (from Xc/H1) + B (from buf), 16 MFMA
    auto step = [&](int kt, int bufb) {
        s16x8 a[4], b[4];
#pragma unroll
        for (int mi = 0; mi < 4; ++mi) {
            int r = mi * 16 + l15;
            int byte = ((r * CH + kt * 32 + kg * 8) * 2) ^ ((r & 7) << 4);
            a[mi] = *(const s16x8*)(lds + byte);
        }
#pragma unroll
        for (int ni = 0; ni < 4; ++ni)
            b[ni] = *(const s16x8*)(lds + bufb + ((wid * 4 + ni) * 64 + lane) * 16);
#pragma unroll
        for (int ni = 0; ni < 4; ++ni)
#pragma unroll
            for (int mi = 0; mi < 4; ++mi)
                acc[mi][ni] = __builtin_amdgcn_mfma_f32_16x16x32_bf16(
                    a[mi], b[ni], acc[mi][ni], 0, 0, 0);
    };

    // ================= GEMM1 =================
    zacc();
#pragma unroll
    for (int kt = 0; kt < 16; ++kt) {
        if (kt < 15) stageB(p1n, kt + 1, (kt & 1) ? BBUF0 : BBUF1);
        else         stageB(p2n, 0,      BBUF0);          // prefetch W2[0] under GELU
        step(kt, (kt & 1) ? BBUF1 : BBUF0);
        __syncthreads();
    }

    // bias1 + GELU -> H1 bf16 into (aliased) LDS, same swizzle
#pragma unroll
    for (int mi = 0; mi < 4; ++mi)
#pragma unroll
        for (int ni = 0; ni < 4; ++ni)
#pragma unroll
            for (int r = 0; r < 4; ++r) {
                float v = gelu_fast(acc[mi][ni][r] + b1v[ni]);
                int row  = mi * 16 + kg * 4 + r;
                int col  = nwoff + ni * 16 + l15;
                int byte = ((row * CH + col) * 2) ^ ((row & 7) << 4);
                *(unsigned short*)(lds + byte) = f2bf(v);
            }
    __syncthreads();   // drains vm (W2[0]) and lgkm (H1 writes)

    // ================= GEMM2 =================
    zacc();
#pragma unroll
    for (int kt = 0; kt < 16; ++kt) {
        if (kt < 15) stageB(p2n, kt + 1, (kt & 1) ? BBUF0 : BBUF1);
        step(kt, (kt & 1) ? BBUF1 : BBUF0);
        if (kt < 15) __syncthreads();      // no barrier needed after the last step
    }

    // ---- epilogue: + b2 + residual x, store fp32 pre-LN (full 64B lines) ----
    const float* xr = x   + (size_t)row0 * DMODEL + n * CH;
    float*       mr = mid + (size_t)row0 * DMODEL + n * CH;
#pragma unroll
    for (int mi = 0; mi < 4; ++mi)
#pragma unroll
        for (int ni = 0; ni < 4; ++ni)
#pragma unroll
            for (int r = 0; r < 4; ++r) {
                int row = mi * 16 + kg * 4 + r;
                int col = nwoff + ni * 16 + l15;
                float v = acc[mi][ni][r] + b2v[ni] + xr[(size_t)row * DMODEL + col];
                mr[(size_t)row * DMODEL + col] = v;
            }
}

// ---------------------------------------------------------------------------
// K2: in-place LayerNorm over rows of `out`.
// ---------------------------------------------------------------------------
__global__ __launch_bounds__(256)
void ln_kernel(float* __restrict__ out,
               const float* __restrict__ g,
               const float* __restrict__ bt)
{
    __shared__ float red[8];
    const int row = blockIdx.x;
    const int tid = threadIdx.x;
    float* p = out + (size_t)row * DMODEL;

    float4 v[4];
    float s = 0.f, ss = 0.f;
#pragma unroll
    for (int i = 0; i < 4; ++i) {
        v[i] = *(const float4*)(p + (i * 256 + tid) * 4);
        s  += v[i].x + v[i].y + v[i].z + v[i].w;
        ss += v[i].x * v[i].x + v[i].y * v[i].y + v[i].z * v[i].z + v[i].w * v[i].w;
    }
#pragma unroll
    for (int o = 32; o > 0; o >>= 1) {
        s  += __shfl_xor(s, o, 64);
        ss += __shfl_xor(ss, o, 64);
    }
    const int wid = tid >> 6, lane = tid & 63;
    if (lane == 0) { red[wid] = s; red[4 + wid] = ss; }
    __syncthreads();
    s  = red[0] + red[1] + red[2] + red[3];
    ss = red[4] + red[5] + red[6] + red[7];
    const float mu   = s * (1.f / DMODEL);
    const float var  = ss * (1.f / DMODEL) - mu * mu;
    const float rstd = rsqrtf(var + 1e-5f);

#pragma unroll
    for (int i = 0; i < 4; ++i) {
        int c = (i * 256 + tid) * 4;
        float4 gv = *(const float4*)(g + c);
        float4 bv = *(const float4*)(bt + c);
        float4 o;
        o.x = (v[i].x - mu) * rstd * gv.x + bv.x;
        o.y = (v[i].y - mu) * rstd * gv.y + bv.y;
        o.z = (v[i].z - mu) * rstd * gv.z + bv.z;
        o.w = (v[i].w - mu) * rstd * gv.w + bv.w;
        *(float4*)(p + c) = o;
    }
}

// ---------------------------------------------------------------------------
extern "C" void kernel_launch(void* const* d_in, const int* in_sizes, int n_in,
                              void* d_out, int out_size, void* d_ws, size_t ws_size,
                              hipStream_t stream)
{
    const float* x    = (const float*)d_in[0];
    const float* w1   = (const float*)d_in[1];
    const float* b1   = (const float*)d_in[2];
    const float* w2   = (const float*)d_in[3];
    const float* b2   = (const float*)d_in[4];
    const float* ln_g = (const float*)d_in[5];
    const float* ln_b = (const float*)d_in[6];
    float* out = (float*)d_out;

    unsigned short* p1 = (unsigned short*)d_ws;           // 4 MiB packed W1
    unsigned short* p2 = p1 + (size_t)NCH * CH * CH;      // 4 MiB packed W2

    wprep_kernel<<<dim3(16, 8, 16), dim3(64, 4), 0, stream>>>(w1, w2, p1, p2);
    mlp_kernel<<<dim3(TOKENS / BM, NCH), dim3(512), 0, stream>>>(x, p1, p2, b1, b2, out);
    ln_kernel<<<dim3(TOKENS), dim3(256), 0, stream>>>(out, ln_g, ln_b);
}

// Round 10
// 370.027 us; speedup vs baseline: 1.3302x; 1.3302x over previous
//
#include <hip/hip_runtime.h>
#include <hip/hip_bf16.h>

#define TOKENS 16384
#define DMODEL 4096
#define NCH 8
#define CH 512
#define BM 64

typedef short s16x8 __attribute__((ext_vector_type(8)));
typedef float f32x4 __attribute__((ext_vector_type(4)));

__device__ __forceinline__ unsigned short f2bf(float f) {
    unsigned u = __float_as_uint(f);
    u += 0x7fffu + ((u >> 16) & 1u);
    return (unsigned short)(u >> 16);
}

// tanh-form GELU via single v_exp: gelu(x) = x - x/(e+1), e = exp(1.5957691*(x+0.044715x^3))
__device__ __forceinline__ float gelu_fast(float x) {
    float u = 1.5957691216057308f * x * (1.0f + 0.044715f * x * x);
    float e = __expf(u);
    return x - x * __builtin_amdgcn_rcpf(e + 1.0f);
}

// ---------------------------------------------------------------------------
// K0: weight prep into MFMA-fragment-packed layout.
// w[n][c][d] fp32 -> P[n][kt*32+nb][lane][8] bf16; the 16B at (kt,nb,lane)
// holds W[kt*32+kg*8+j][nb*16+l15], j=0..7 (kg=lane>>4, l15=lane&15).
// One (kt,nb) line = 64 lanes x 16B = 1KB contiguous -> global_load_lds ready.
// ---------------------------------------------------------------------------
__global__ __launch_bounds__(256)
void wprep_kernel(const float* __restrict__ w1, const float* __restrict__ w2,
                  unsigned short* __restrict__ p1, unsigned short* __restrict__ p2)
{
    const int lane = threadIdx.x;          // 0..63
    const int sub  = threadIdx.y;          // 0..3
    const int kt   = blockIdx.x;           // 0..15
    const int nb   = blockIdx.y * 4 + sub; // 0..31
    const int which = blockIdx.z >> 3;
    const int n     = blockIdx.z & 7;

    const int kg  = lane >> 4;
    const int l15 = lane & 15;

    const float* src = (which ? w2 : w1) + (size_t)n * CH * CH;
    unsigned short* dst = (which ? p2 : p1) + (size_t)n * CH * CH
                        + ((size_t)(kt * 32 + nb) * 64 + lane) * 8;

    unsigned short v[8];
#pragma unroll
    for (int j = 0; j < 8; ++j)
        v[j] = f2bf(src[(size_t)(kt * 32 + kg * 8 + j) * CH + nb * 16 + l15]);

    uint4 q;
    q.x = (unsigned)v[0] | ((unsigned)v[1] << 16);
    q.y = (unsigned)v[2] | ((unsigned)v[3] << 16);
    q.z = (unsigned)v[4] | ((unsigned)v[5] << 16);
    q.w = (unsigned)v[6] | ((unsigned)v[7] << 16);
    *(uint4*)dst = q;
}

// ---------------------------------------------------------------------------
// K1: fused chunk MLP, BARRIER-FREE K-loop with wave-private B staging and
// counted vmcnt (T4). grid = (TOKENS/BM, NCH); block = 512 (8 waves).
// Wave owns all 64 M rows x a 64-wide N slice (acc 4x4).
// LDS: [0,64K) Xc bf16 (XOR-swizzled; aliased to H1 after GEMM1)
//      [64K,96K) B buf0   [96K,128K) B buf1
// B buffers are WAVE-PRIVATE: wave wid stages and reads only bytes
// [wid*4KB, wid*4KB+4KB) of each buffer -> no inter-wave dependency ->
// no __syncthreads() in the K-loop; per-wave s_waitcnt vmcnt(4) instead.
// Only 2 barriers remain (around the GELU / H1-aliasing transition).
// ---------------------------------------------------------------------------
#define XC_BYTES (BM * CH * 2)        // 65536
#define BBUF0    XC_BYTES
#define BBUF1    (XC_BYTES + 32768)

__global__ __launch_bounds__(512, 1)
void mlp_kernel(const float* __restrict__ x,
                const unsigned short* __restrict__ p1,
                const unsigned short* __restrict__ p2,
                const float* __restrict__ b1,
                const float* __restrict__ b2,
                float* __restrict__ mid)
{
    __shared__ unsigned char lds[XC_BYTES + 2 * 32768];   // 128 KB
    const int tile = blockIdx.x;
    const int n    = blockIdx.y;
    const int tid  = threadIdx.x;
    const int wid  = tid >> 6;          // 0..7
    const int lane = tid & 63;
    const int row0 = tile * BM;

    const unsigned short* p1n = p1 + (size_t)n * CH * CH;
    const unsigned short* p2n = p2 + (size_t)n * CH * CH;

    // stage this wave's 4 x 1KB B-frag lines of k-tile kt into buffer `bufb`
    auto stageB = [&](const unsigned short* pk, int kt, int bufb) {
#pragma unroll
        for (int i = 0; i < 4; ++i) {
            const unsigned short* src = pk + ((size_t)(kt * 32 + wid * 4 + i) * 64 + lane) * 8;
            unsigned char* dstp = lds + bufb + (wid * 4 + i) * 1024;  // wave-uniform
            __builtin_amdgcn_global_load_lds(
                (const __attribute__((address_space(1))) void*)src,
                (__attribute__((address_space(3))) void*)dstp,
                16, 0, 0);
        }
    };

    // ---- prologue: issue B1[0] -> buf0, then stage Xc (fp32->bf16, swizzled)
    stageB(p1n, 0, BBUF0);
    {
        const float* xc = x + (size_t)row0 * DMODEL + n * CH;
#pragma unroll
        for (int it = 0; it < 16; ++it) {
            int f = it * 512 + tid;          // float4 index, 128 per row, 64 rows
            int r = f >> 7;
            int c = (f & 127) << 2;
            const float4 v = *(const float4*)(xc + (size_t)r * DMODEL + c);
            unsigned lo = (unsigned)f2bf(v.x) | ((unsigned)f2bf(v.y) << 16);
            unsigned hi = (unsigned)f2bf(v.z) | ((unsigned)f2bf(v.w) << 16);
            int byte = ((r * CH + c) * 2) ^ ((r & 7) << 4);
            *(uint2*)(lds + byte) = make_uint2(lo, hi);
        }
    }
    __syncthreads();   // drains vm (B1[0]) and lgkm (Xc writes)

    const int nwoff = wid * 64;         // wave's N offset within the chunk
    const int l15   = lane & 15;
    const int kg    = lane >> 4;

    float b1v[4], b2v[4];
#pragma unroll
    for (int ni = 0; ni < 4; ++ni) {
        int col = n * CH + nwoff + ni * 16 + l15;
        b1v[ni] = b1[col];
        b2v[ni] = b2[col];
    }

    f32x4 acc[4][4];
    auto zacc = [&]() {
#pragma unroll
        for (int mi = 0; mi < 4; ++mi)
#pragma unroll
            for (int ni = 0; ni < 4; ++ni)
                acc[mi][ni] = (f32x4){0.f, 0.f, 0.f, 0.f};
    };

    // one kt compute step: ds_read A (from Xc/H1) + B (own lines), 16 MFMA
    auto step = [&](int kt, int bufb) {
        s16x8 a[4], b[4];
#pragma unroll
        for (int mi = 0; mi < 4; ++mi) {
            int r = mi * 16 + l15;
            int byte = ((r * CH + kt * 32 + kg * 8) * 2) ^ ((r & 7) << 4);
            a[mi] = *(const s16x8*)(lds + byte);
        }
#pragma unroll
        for (int ni = 0; ni < 4; ++ni)
            b[ni] = *(const s16x8*)(lds + bufb + ((wid * 4 + ni) * 64 + lane) * 16);
#pragma unroll
        for (int ni = 0; ni < 4; ++ni)
#pragma unroll
            for (int mi = 0; mi < 4; ++mi)
                acc[mi][ni] = __builtin_amdgcn_mfma_f32_16x16x32_bf16(
                    a[mi], b[ni], acc[mi][ni], 0, 0, 0);
    };

    // ================= GEMM1 (barrier-free K-loop) =================
    zacc();
#pragma unroll 2
    for (int kt = 0; kt < 16; ++kt) {
        if (kt < 15) stageB(p1n, kt + 1, (kt & 1) ? BBUF0 : BBUF1);
        else         stageB(p2n, 0,      BBUF0);          // prefetch W2[0]
        // wait for THIS wave's kt-stage (the 4 just-issued remain in flight)
        asm volatile("s_waitcnt vmcnt(4)" ::: "memory");
        step(kt, (kt & 1) ? BBUF1 : BBUF0);
    }

    __syncthreads();   // all waves done reading Xc (drains W2[0] stage too)

    // bias1 + GELU -> H1 bf16 into (aliased) LDS, same swizzle
#pragma unroll
    for (int mi = 0; mi < 4; ++mi)
#pragma unroll
        for (int ni = 0; ni < 4; ++ni)
#pragma unroll
            for (int r = 0; r < 4; ++r) {
                float v = gelu_fast(acc[mi][ni][r] + b1v[ni]);
                int row  = mi * 16 + kg * 4 + r;
                int col  = nwoff + ni * 16 + l15;
                int byte = ((row * CH + col) * 2) ^ ((row & 7) << 4);
                *(unsigned short*)(lds + byte) = f2bf(v);
            }
    __syncthreads();   // H1 visible to all waves

    // ================= GEMM2 (barrier-free K-loop) =================
    zacc();
#pragma unroll 2
    for (int kt = 0; kt < 16; ++kt) {
        if (kt < 15) {
            stageB(p2n, kt + 1, (kt & 1) ? BBUF0 : BBUF1);
            asm volatile("s_waitcnt vmcnt(4)" ::: "memory");
        } else {
            asm volatile("s_waitcnt vmcnt(0)" ::: "memory");
        }
        step(kt, (kt & 1) ? BBUF1 : BBUF0);
    }

    // ---- epilogue: + b2 + residual x, store fp32 pre-LN (full 64B lines) ----
    const float* xr = x   + (size_t)row0 * DMODEL + n * CH;
    float*       mr = mid + (size_t)row0 * DMODEL + n * CH;
#pragma unroll
    for (int mi = 0; mi < 4; ++mi)
#pragma unroll
        for (int ni = 0; ni < 4; ++ni)
#pragma unroll
            for (int r = 0; r < 4; ++r) {
                int row = mi * 16 + kg * 4 + r;
                int col = nwoff + ni * 16 + l15;
                float v = acc[mi][ni][r] + b2v[ni] + xr[(size_t)row * DMODEL + col];
                mr[(size_t)row * DMODEL + col] = v;
            }
}

// ---------------------------------------------------------------------------
// K2: in-place LayerNorm over rows of `out`.
// ---------------------------------------------------------------------------
__global__ __launch_bounds__(256)
void ln_kernel(float* __restrict__ out,
               const float* __restrict__ g,
               const float* __restrict__ bt)
{
    __shared__ float red[8];
    const int row = blockIdx.x;
    const int tid = threadIdx.x;
    float* p = out + (size_t)row * DMODEL;

    float4 v[4];
    float s = 0.f, ss = 0.f;
#pragma unroll
    for (int i = 0; i < 4; ++i) {
        v[i] = *(const float4*)(p + (i * 256 + tid) * 4);
        s  += v[i].x + v[i].y + v[i].z + v[i].w;
        ss += v[i].x * v[i].x + v[i].y * v[i].y + v[i].z * v[i].z + v[i].w * v[i].w;
    }
#pragma unroll
    for (int o = 32; o > 0; o >>= 1) {
        s  += __shfl_xor(s, o, 64);
        ss += __shfl_xor(ss, o, 64);
    }
    const int wid = tid >> 6, lane = tid & 63;
    if (lane == 0) { red[wid] = s; red[4 + wid] = ss; }
    __syncthreads();
    s  = red[0] + red[1] + red[2] + red[3];
    ss = red[4] + red[5] + red[6] + red[7];
    const float mu   = s * (1.f / DMODEL);
    const float var  = ss * (1.f / DMODEL) - mu * mu;
    const float rstd = rsqrtf(var + 1e-5f);

#pragma unroll
    for (int i = 0; i < 4; ++i) {
        int c = (i * 256 + tid) * 4;
        float4 gv = *(const float4*)(g + c);
        float4 bv = *(const float4*)(bt + c);
        float4 o;
        o.x = (v[i].x - mu) * rstd * gv.x + bv.x;
        o.y = (v[i].y - mu) * rstd * gv.y + bv.y;
        o.z = (v[i].z - mu) * rstd * gv.z + bv.z;
        o.w = (v[i].w - mu) * rstd * gv.w + bv.w;
        *(float4*)(p + c) = o;
    }
}

// ---------------------------------------------------------------------------
extern "C" void kernel_launch(void* const* d_in, const int* in_sizes, int n_in,
                              void* d_out, int out_size, void* d_ws, size_t ws_size,
                              hipStream_t stream)
{
    const float* x    = (const float*)d_in[0];
    const float* w1   = (const float*)d_in[1];
    const float* b1   = (const float*)d_in[2];
    const float* w2   = (const float*)d_in[3];
    const float* b2   = (const float*)d_in[4];
    const float* ln_g = (const float*)d_in[5];
    const float* ln_b = (const float*)d_in[6];
    float* out = (float*)d_out;

    unsigned short* p1 = (unsigned short*)d_ws;           // 4 MiB packed W1
    unsigned short* p2 = p1 + (size_t)NCH * CH * CH;      // 4 MiB packed W2

    wprep_kernel<<<dim3(16, 8, 16), dim3(64, 4), 0, stream>>>(w1, w2, p1, p2);
    mlp_kernel<<<dim3(TOKENS / BM, NCH), dim3(512), 0, stream>>>(x, p1, p2, b1, b2, out);
    ln_kernel<<<dim3(TOKENS), dim3(256), 0, stream>>>(out, ln_g, ln_b);
}

// Round 11
// 342.397 us; speedup vs baseline: 1.4375x; 1.0807x over previous
//
#include <hip/hip_runtime.h>
#include <hip/hip_bf16.h>

#define TOKENS 16384
#define DMODEL 4096
#define NCH 8
#define CH 512
#define BM 64

typedef short s16x8 __attribute__((ext_vector_type(8)));
typedef float f32x4 __attribute__((ext_vector_type(4)));

__device__ __forceinline__ unsigned short f2bf(float f) {
    unsigned u = __float_as_uint(f);
    u += 0x7fffu + ((u >> 16) & 1u);
    return (unsigned short)(u >> 16);
}

// tanh-form GELU via single v_exp: gelu(x) = x - x/(e+1), e = exp(1.5957691*(x+0.044715x^3))
__device__ __forceinline__ float gelu_fast(float x) {
    float u = 1.5957691216057308f * x * (1.0f + 0.044715f * x * x);
    float e = __expf(u);
    return x - x * __builtin_amdgcn_rcpf(e + 1.0f);
}

// ---------------------------------------------------------------------------
// K0: weight prep into MFMA-fragment-packed layout.
// w[n][c][d] fp32 -> P[n][kt*32+nb][lane][8] bf16; the 16B at (kt,nb,lane)
// holds W[kt*32+kg*8+j][nb*16+l15], j=0..7 (kg=lane>>4, l15=lane&15).
// One (kt,nb) line = 64 lanes x 16B = 1KB contiguous -> global_load_lds ready.
// ---------------------------------------------------------------------------
__global__ __launch_bounds__(256)
void wprep_kernel(const float* __restrict__ w1, const float* __restrict__ w2,
                  unsigned short* __restrict__ p1, unsigned short* __restrict__ p2)
{
    const int lane = threadIdx.x;          // 0..63
    const int sub  = threadIdx.y;          // 0..3
    const int kt   = blockIdx.x;           // 0..15
    const int nb   = blockIdx.y * 4 + sub; // 0..31
    const int which = blockIdx.z >> 3;
    const int n     = blockIdx.z & 7;

    const int kg  = lane >> 4;
    const int l15 = lane & 15;

    const float* src = (which ? w2 : w1) + (size_t)n * CH * CH;
    unsigned short* dst = (which ? p2 : p1) + (size_t)n * CH * CH
                        + ((size_t)(kt * 32 + nb) * 64 + lane) * 8;

    unsigned short v[8];
#pragma unroll
    for (int j = 0; j < 8; ++j)
        v[j] = f2bf(src[(size_t)(kt * 32 + kg * 8 + j) * CH + nb * 16 + l15]);

    uint4 q;
    q.x = (unsigned)v[0] | ((unsigned)v[1] << 16);
    q.y = (unsigned)v[2] | ((unsigned)v[3] << 16);
    q.z = (unsigned)v[4] | ((unsigned)v[5] << 16);
    q.w = (unsigned)v[6] | ((unsigned)v[7] << 16);
    *(uint4*)dst = q;
}

// ---------------------------------------------------------------------------
// K1: fused chunk MLP. Barrier-free K-loops, wave-private B staging via
// global_load_lds, counted vmcnt (steady-state vmcnt(8), never 0 mid-loop),
// TRIPLE-buffered B (issue->consume distance 2), and a PER-BLOCK K-OFFSET
// kt0 = (tile>>3)&15 so co-resident blocks read different weight lines
// (anti thundering-herd on L2). grid = (TOKENS/BM, NCH); block = 512.
// LDS: [0,64K) Xc bf16 (XOR-swizzled; aliased to H1)  [64K..160K) 3x32K B bufs.
// ---------------------------------------------------------------------------
#define XC_BYTES (BM * CH * 2)        // 65536
#define BBUF(i)  (XC_BYTES + (i) * 32768)

__global__ __launch_bounds__(512, 1)
void mlp_kernel(const float* __restrict__ x,
                const unsigned short* __restrict__ p1,
                const unsigned short* __restrict__ p2,
                const float* __restrict__ b1,
                const float* __restrict__ b2,
                float* __restrict__ mid)
{
    __shared__ unsigned char lds[XC_BYTES + 3 * 32768];   // 160 KB
    const int tile = blockIdx.x;
    const int n    = blockIdx.y;
    const int tid  = threadIdx.x;
    const int wid  = tid >> 6;          // 0..7
    const int lane = tid & 63;
    const int row0 = tile * BM;
    const int kt0  = (tile >> 3) & 15;  // per-block K rotation (herd-breaker)

    const unsigned short* p1n = p1 + (size_t)n * CH * CH;
    const unsigned short* p2n = p2 + (size_t)n * CH * CH;

    const int nwoff = wid * 64;
    const int l15   = lane & 15;
    const int kg    = lane >> 4;

    // bias loads issued FIRST so the prologue barrier drains them (keeps
    // in-loop vmcnt counting pure: only B stages outstanding in the K-loops)
    float b1v[4], b2v[4];
#pragma unroll
    for (int ni = 0; ni < 4; ++ni) {
        int col = n * CH + nwoff + ni * 16 + l15;
        b1v[ni] = b1[col];
        b2v[ni] = b2[col];
    }

    // stage this wave's 4 x 1KB B-frag lines of physical k-tile kt -> buffer
    auto stageB = [&](const unsigned short* pk, int kt, int bufb) {
#pragma unroll
        for (int i = 0; i < 4; ++i) {
            const unsigned short* src = pk + ((size_t)(kt * 32 + wid * 4 + i) * 64 + lane) * 8;
            unsigned char* dstp = lds + bufb + (wid * 4 + i) * 1024;  // wave-uniform
            __builtin_amdgcn_global_load_lds(
                (const __attribute__((address_space(1))) void*)src,
                (__attribute__((address_space(3))) void*)dstp,
                16, 0, 0);
        }
    };

    // ---- prologue: issue steps 0,1 (GEMM1 kt0, kt0+1), then stage Xc ----
    stageB(p1n, kt0, BBUF(0));
    stageB(p1n, (kt0 + 1) & 15, BBUF(1));
    {
        const float* xc = x + (size_t)row0 * DMODEL + n * CH;
#pragma unroll
        for (int it = 0; it < 16; ++it) {
            int f = it * 512 + tid;          // float4 index, 128 per row, 64 rows
            int r = f >> 7;
            int c = (f & 127) << 2;
            const float4 v = *(const float4*)(xc + (size_t)r * DMODEL + c);
            unsigned lo = (unsigned)f2bf(v.x) | ((unsigned)f2bf(v.y) << 16);
            unsigned hi = (unsigned)f2bf(v.z) | ((unsigned)f2bf(v.w) << 16);
            int byte = ((r * CH + c) * 2) ^ ((r & 7) << 4);
            *(uint2*)(lds + byte) = make_uint2(lo, hi);
        }
    }
    __syncthreads();   // drains vm (steps 0,1 + biases) and lgkm (Xc writes)

    f32x4 acc[4][4];
    auto zacc = [&]() {
#pragma unroll
        for (int mi = 0; mi < 4; ++mi)
#pragma unroll
            for (int ni = 0; ni < 4; ++ni)
                acc[mi][ni] = (f32x4){0.f, 0.f, 0.f, 0.f};
    };

    // one kt compute step: ds_read A (Xc/H1 at physical kt) + B (own lines)
    auto step = [&](int kt, int bufb) {
        s16x8 a[4], b[4];
#pragma unroll
        for (int mi = 0; mi < 4; ++mi) {
            int r = mi * 16 + l15;
            int byte = ((r * CH + kt * 32 + kg * 8) * 2) ^ ((r & 7) << 4);
            a[mi] = *(const s16x8*)(lds + byte);
        }
#pragma unroll
        for (int ni = 0; ni < 4; ++ni)
            b[ni] = *(const s16x8*)(lds + bufb + ((wid * 4 + ni) * 64 + lane) * 16);
#pragma unroll
        for (int ni = 0; ni < 4; ++ni)
#pragma unroll
            for (int mi = 0; mi < 4; ++mi)
                acc[mi][ni] = __builtin_amdgcn_mfma_f32_16x16x32_bf16(
                    a[mi], b[ni], acc[mi][ni], 0, 0, 0);
    };

    // ================= GEMM1: continuous steps c = 0..15 =================
    zacc();
#pragma unroll
    for (int c = 0; c < 16; ++c) {
        // issue step c+2 (rotates into the buffer consumed at step c-1)
        if (c + 2 < 16) stageB(p1n, ((c + 2 + kt0) & 15), BBUF((c + 2) % 3));
        else            stageB(p2n, ((c + 2 - 16 + kt0) & 15), BBUF((c + 2) % 3));
        // steady state: steps c+1, c+2 in flight (8 gll); step c complete
        asm volatile("s_waitcnt vmcnt(8)" ::: "memory");
        step((c + kt0) & 15, BBUF(c % 3));
    }

    __syncthreads();   // Xc reads done; drains the 2 cross-boundary stages

    // bias1 + GELU -> H1 bf16 into (aliased) LDS, same swizzle
#pragma unroll
    for (int mi = 0; mi < 4; ++mi)
#pragma unroll
        for (int ni = 0; ni < 4; ++ni)
#pragma unroll
            for (int r = 0; r < 4; ++r) {
                float v = gelu_fast(acc[mi][ni][r] + b1v[ni]);
                int row  = mi * 16 + kg * 4 + r;
                int col  = nwoff + ni * 16 + l15;
                int byte = ((row * CH + col) * 2) ^ ((row & 7) << 4);
                *(unsigned short*)(lds + byte) = f2bf(v);
            }
    __syncthreads();   // H1 visible to all waves

    // ================= GEMM2: continuous steps c = 16..31 =================
    zacc();
#pragma unroll
    for (int c = 16; c < 32; ++c) {
        if (c + 2 < 32) {
            stageB(p2n, ((c + 2 - 16 + kt0) & 15), BBUF((c + 2) % 3));
            asm volatile("s_waitcnt vmcnt(8)" ::: "memory");
        } else if (c == 30) {
            asm volatile("s_waitcnt vmcnt(4)" ::: "memory");
        } else {
            asm volatile("s_waitcnt vmcnt(0)" ::: "memory");
        }
        step(((c - 16) + kt0) & 15, BBUF(c % 3));
    }

    // ---- epilogue: + b2 + residual x, store fp32 pre-LN (full 64B lines) ----
    const float* xr = x   + (size_t)row0 * DMODEL + n * CH;
    float*       mr = mid + (size_t)row0 * DMODEL + n * CH;
#pragma unroll
    for (int mi = 0; mi < 4; ++mi)
#pragma unroll
        for (int ni = 0; ni < 4; ++ni)
#pragma unroll
            for (int r = 0; r < 4; ++r) {
                int row = mi * 16 + kg * 4 + r;
                int col = nwoff + ni * 16 + l15;
                float v = acc[mi][ni][r] + b2v[ni] + xr[(size_t)row * DMODEL + col];
                mr[(size_t)row * DMODEL + col] = v;
            }
}

// ---------------------------------------------------------------------------
// K2: in-place LayerNorm over rows of `out`.
// ---------------------------------------------------------------------------
__global__ __launch_bounds__(256)
void ln_kernel(float* __restrict__ out,
               const float* __restrict__ g,
               const float* __restrict__ bt)
{
    __shared__ float red[8];
    const int row = blockIdx.x;
    const int tid = threadIdx.x;
    float* p = out + (size_t)row * DMODEL;

    float4 v[4];
    float s = 0.f, ss = 0.f;
#pragma unroll
    for (int i = 0; i < 4; ++i) {
        v[i] = *(const float4*)(p + (i * 256 + tid) * 4);
        s  += v[i].x + v[i].y + v[i].z + v[i].w;
        ss += v[i].x * v[i].x + v[i].y * v[i].y + v[i].z * v[i].z + v[i].w * v[i].w;
    }
#pragma unroll
    for (int o = 32; o > 0; o >>= 1) {
        s  += __shfl_xor(s, o, 64);
        ss += __shfl_xor(ss, o, 64);
    }
    const int wid = tid >> 6, lane = tid & 63;
    if (lane == 0) { red[wid] = s; red[4 + wid] = ss; }
    __syncthreads();
    s  = red[0] + red[1] + red[2] + red[3];
    ss = red[4] + red[5] + red[6] + red[7];
    const float mu   = s * (1.f / DMODEL);
    const float var  = ss * (1.f / DMODEL) - mu * mu;
    const float rstd = rsqrtf(var + 1e-5f);

#pragma unroll
    for (int i = 0; i < 4; ++i) {
        int c = (i * 256 + tid) * 4;
        float4 gv = *(const float4*)(g + c);
        float4 bv = *(const float4*)(bt + c);
        float4 o;
        o.x = (v[i].x - mu) * rstd * gv.x + bv.x;
        o.y = (v[i].y - mu) * rstd * gv.y + bv.y;
        o.z = (v[i].z - mu) * rstd * gv.z + bv.z;
        o.w = (v[i].w - mu) * rstd * gv.w + bv.w;
        *(float4*)(p + c) = o;
    }
}

// ---------------------------------------------------------------------------
extern "C" void kernel_launch(void* const* d_in, const int* in_sizes, int n_in,
                              void* d_out, int out_size, void* d_ws, size_t ws_size,
                              hipStream_t stream)
{
    const float* x    = (const float*)d_in[0];
    const float* w1   = (const float*)d_in[1];
    const float* b1   = (const float*)d_in[2];
    const float* w2   = (const float*)d_in[3];
    const float* b2   = (const float*)d_in[4];
    const float* ln_g = (const float*)d_in[5];
    const float* ln_b = (const float*)d_in[6];
    float* out = (float*)d_out;

    unsigned short* p1 = (unsigned short*)d_ws;           // 4 MiB packed W1
    unsigned short* p2 = p1 + (size_t)NCH * CH * CH;      // 4 MiB packed W2

    wprep_kernel<<<dim3(16, 8, 16), dim3(64, 4), 0, stream>>>(w1, w2, p1, p2);
    mlp_kernel<<<dim3(TOKENS / BM, NCH), dim3(512), 0, stream>>>(x, p1, p2, b1, b2, out);
    ln_kernel<<<dim3(TOKENS), dim3(256), 0, stream>>>(out, ln_g, ln_b);
}